// Round 15
// baseline (173.271 us; speedup 1.0000x reference)
//
#include <hip/hip_runtime.h>
#include <hip/hip_bf16.h>
#include <hip/hip_fp16.h>

#define N_NODES 50000
#define N_EDGES 800000
#define DIM     128
#define NG      64
#define CAP     48     // CSR capacity/node (multiple of 8 and 4)
#define AGG_EB  256    // edge partial-sum blocks
#define LAXP    136    // padded lax stride (f16 elems)
#define NODE_B  782    // ceil(50000/64) k_node blocks, 64 nodes each

#define NBIN    196    // ceil(50000/256) bins of 256 nodes (dst>>8)
#define SORT_B  250    // S1/S3 blocks
#define EPB     3200   // edges per sort block (250*3200 = 800000 exact)

#define CAST_B  1563   // ceil(400000/256)
#define VB_B    129
#define WF_B    8

typedef float  f2_t  __attribute__((ext_vector_type(2)));
typedef float  f32x4 __attribute__((ext_vector_type(4)));
typedef _Float16 f16x8 __attribute__((ext_vector_type(8)));

__device__ __forceinline__ void fma16(float* acc, float wgt, uint4 q) {
    unsigned u[4] = {q.x, q.y, q.z, q.w};
    #pragma unroll
    for (int c = 0; c < 4; c++) {
        f2_t lo = __builtin_amdgcn_cvt_pk_f32_fp8((int)u[c], false);
        f2_t hi = __builtin_amdgcn_cvt_pk_f32_fp8((int)u[c], true);
        acc[4 * c + 0] = fmaf(wgt, lo.x, acc[4 * c + 0]);
        acc[4 * c + 1] = fmaf(wgt, lo.y, acc[4 * c + 1]);
        acc[4 * c + 2] = fmaf(wgt, hi.x, acc[4 * c + 2]);
        acc[4 * c + 3] = fmaf(wgt, hi.y, acc[4 * c + 3]);
    }
}

// ---- prep: S1 bin-count | cast x->fp8 | v=W2@Wc | W1->f16 B-fragments ----
__global__ void k_prep(const int* __restrict__ ei, int* __restrict__ binCnt,
                       const float4* __restrict__ x4, uint4* __restrict__ xq4,
                       const float* __restrict__ W2, const float* __restrict__ Wc,
                       const float* __restrict__ b2, float* __restrict__ v,
                       float* __restrict__ beta2,
                       const float* __restrict__ W1, f16x8* __restrict__ w1f) {
    __shared__ float red[4];
    __shared__ int hist[256];
    int bid = blockIdx.x, t = threadIdx.x;
    if (bid < SORT_B) {
        hist[t] = 0;
        __syncthreads();
        int base = bid * EPB;
        for (int r = 0; r < 13; r++) {
            int idx = r * 256 + t;
            if (idx < EPB) {
                int d = ei[N_EDGES + base + idx];
                atomicAdd(&hist[d >> 8], 1);
            }
        }
        __syncthreads();
        if (t < NBIN && hist[t] > 0) atomicAdd(&binCnt[t], hist[t]);
    } else if (bid < SORT_B + CAST_B) {
        int idx = (bid - SORT_B) * 256 + t;  // 16 dims/thread
        if (idx < N_NODES * DIM / 16) {
            uint4 o;
            unsigned* op = (unsigned*)&o;
            #pragma unroll
            for (int q = 0; q < 4; q++) {
                float4 f = x4[idx * 4 + q];
                int p = 0;
                p = __builtin_amdgcn_cvt_pk_fp8_f32(f.x, f.y, p, false);
                p = __builtin_amdgcn_cvt_pk_fp8_f32(f.z, f.w, p, true);
                op[q] = (unsigned)p;
            }
            xq4[idx] = o;
        }
    } else if (bid < SORT_B + CAST_B + VB_B) {
        int b = bid - (SORT_B + CAST_B);     // 0..128
        float p = 0.f;
        if (t < DIM) p = (b < DIM) ? W2[b * DIM + t] * Wc[t] : b2[t] * Wc[t];
        #pragma unroll
        for (int off = 32; off > 0; off >>= 1) p += __shfl_down(p, off, 64);
        if ((t & 63) == 0) red[t >> 6] = p;
        __syncthreads();
        if (t == 0) {
            float s = red[0] + red[1];
            if (b < DIM) v[b] = s; else beta2[0] = s;
        }
    } else {
        // W1 -> B-fragment layout for mfma_f32_16x16x32_f16
        int idx = (bid - (SORT_B + CAST_B + VB_B)) * 256 + t;   // 0..2047
        int ntile = idx >> 8, kb = (idx >> 6) & 3, l = idx & 63;
        int kbase = kb * 32 + (l >> 4) * 8;
        int n = ntile * 16 + (l & 15);
        f16x8 o;
        #pragma unroll
        for (int j = 0; j < 8; j++) o[j] = (_Float16)W1[(kbase + j) * DIM + n];
        w1f[idx] = o;
    }
}

// ---- S3 (scan fused in): per-block scan of binCnt, claim ranges, scatter ----
__global__ void k_scatter(const int* __restrict__ ei, const int* __restrict__ binCnt,
                          int* __restrict__ binCur, int* __restrict__ binOff,
                          unsigned int* __restrict__ sorted) {
    __shared__ int soff[256];
    __shared__ int hist[256];
    __shared__ int cur[256];
    int bid = blockIdx.x, t = threadIdx.x;
    int c = (t < NBIN) ? binCnt[t] : 0;
    soff[t] = c;
    #pragma unroll
    for (int o = 1; o < 256; o <<= 1) {
        __syncthreads();
        int v2 = (t >= o) ? soff[t - o] : 0;
        __syncthreads();
        soff[t] += v2;
    }
    __syncthreads();
    int excl = soff[t] - c;
    if (bid == 0 && t < NBIN) binOff[t] = excl;
    hist[t] = 0;
    __syncthreads();
    int base = bid * EPB;
    for (int r = 0; r < 13; r++) {
        int idx = r * 256 + t;
        if (idx < EPB) {
            int d = ei[N_EDGES + base + idx];
            atomicAdd(&hist[d >> 8], 1);
        }
    }
    __syncthreads();
    if (t < NBIN && hist[t] > 0) cur[t] = excl + atomicAdd(&binCur[t], hist[t]);
    __syncthreads();
    for (int r = 0; r < 13; r++) {
        int idx = r * 256 + t;
        if (idx < EPB) {
            int e = base + idx;
            int s = ei[e];
            int d = ei[N_EDGES + e];
            int pos = atomicAdd(&cur[d >> 8], 1);
            sorted[pos] = (unsigned)s | ((unsigned)(d & 255) << 16);
        }
    }
}

// ---- S4a: per-node degree from bin-sorted edges (LDS count) ----
__global__ void k_deg(const unsigned int* __restrict__ sorted,
                      const int* __restrict__ binOff, int* __restrict__ deg) {
    __shared__ int cnt[256];
    int b = blockIdx.x, t = threadIdx.x;
    cnt[t] = 0;
    __syncthreads();
    int lo = binOff[b];
    int hi = (b == NBIN - 1) ? N_EDGES : binOff[b + 1];
    for (int i = lo + t; i < hi; i += 256)
        atomicAdd(&cnt[sorted[i] >> 16], 1);
    __syncthreads();
    int node = b * 256 + t;
    if (node < N_NODES) deg[node] = cnt[t];
}

// ---- S4b: build stamped CSR (LDS cursors; deg[src] plain load) ----
__global__ void k_build(const unsigned int* __restrict__ sorted,
                        const int* __restrict__ binOff, const int* __restrict__ deg,
                        unsigned int* __restrict__ csr) {
    __shared__ int cur[256];
    int b = blockIdx.x, t = threadIdx.x;
    cur[t] = 0;
    __syncthreads();
    int lo = binOff[b];
    int hi = (b == NBIN - 1) ? N_EDGES : binOff[b + 1];
    for (int i = lo + t; i < hi; i += 256) {
        unsigned e = sorted[i];
        unsigned src = e & 0xFFFFu;
        unsigned dLow = e >> 16;
        int pos = atomicAdd(&cur[dLow], 1);
        if (pos < CAP) {
            float w = rsqrtf((float)deg[src] + 1.f);
            unsigned hw = (unsigned)__half_as_ushort(__float2half(w));
            csr[(b * 256 + dLow) * CAP + pos] = src | (hw << 16);
        }
    }
}

// ---- fused: gather(fp8 x) -> MFMA @W1 -> relu -> dot v -> z2 ----
// Octet-per-node: 8 lanes x uint4 = 128 fp8 dims; wave = 8 nodes; block = 64 nodes.
__global__ __launch_bounds__(512) void k_node(
    const uint4* __restrict__ xq4,          // fp8 x; row = 8 uint4
    const unsigned int* __restrict__ csr,   // packed src|f16w
    const f16x8* __restrict__ w1f,          // W1 B-fragments
    const float* __restrict__ b1,
    const float* __restrict__ v, const int* __restrict__ deg,
    float* __restrict__ z2) {
    __shared__ _Float16 laxh[64 * LAXP];    // 64 rows; ~17.4 KB
    __shared__ float redm[64 * 2];
    int tid = threadIdx.x;
    int w = tid >> 6, l = tid & 63;
    int og = l >> 3, ol = l & 7;
    int node0 = blockIdx.x * 64;

    // ---------- aggregation ----------
    {
        int i = node0 + 8 * w + og;
        bool valid = (i < N_NODES);
        int ic = valid ? i : 0;
        int len = valid ? min(deg[ic], CAP) : 0;
        int start = ic * CAP;
        int lm1 = (len > 0) ? len - 1 : 0;
        float di = rsqrtf((float)deg[ic] + 1.f);

        float acc[16];
        #pragma unroll
        for (int k = 0; k < 16; k++) acc[k] = 0.f;
        fma16(acc, di, xq4[(size_t)ic * 8 + ol]);   // self-loop term

        int lenmax = len;                           // wave-uniform max over 8 octets
        lenmax = max(lenmax, __shfl_xor(lenmax, 8, 64));
        lenmax = max(lenmax, __shfl_xor(lenmax, 16, 64));
        lenmax = max(lenmax, __shfl_xor(lenmax, 32, 64));

        for (int j = 0; j < lenmax; j += 2) {
            int j0 = min(j, lm1), j1 = min(j + 1, lm1);
            unsigned e0 = csr[start + j0];           // same addr across octet -> broadcast
            unsigned e1 = csr[start + j1];
            float w0 = (j < len) ? __half2float(__ushort_as_half((unsigned short)(e0 >> 16))) : 0.f;
            float w1 = (j + 1 < len) ? __half2float(__ushort_as_half((unsigned short)(e1 >> 16))) : 0.f;
            uint4 r0 = xq4[(size_t)(e0 & 0xFFFFu) * 8 + ol];
            uint4 r1 = xq4[(size_t)(e1 & 0xFFFFu) * 8 + ol];
            fma16(acc, w0, r0);
            fma16(acc, w1, r1);
        }
        int row = 8 * w + og;
        f16x8 lo, hi;
        #pragma unroll
        for (int k = 0; k < 8; k++) {
            lo[k] = (_Float16)(di * acc[k]);
            hi[k] = (_Float16)(di * acc[8 + k]);
        }
        *(f16x8*)&laxh[row * LAXP + 16 * ol] = lo;
        *(f16x8*)&laxh[row * LAXP + 16 * ol + 8] = hi;
    }
    __syncthreads();

    // ---------- MFMA GEMM: 64x128 @ 128x128; wave w: M-tile (w&3), N-tiles (w>>2)*4.. ----
    {
        int m = w & 3, nh = w >> 2;
        float rs[4] = {0.f, 0.f, 0.f, 0.f};
        #pragma unroll
        for (int c = 0; c < 4; c++) {
            int nt = nh * 4 + c;
            f32x4 accv = {0.f, 0.f, 0.f, 0.f};
            #pragma unroll
            for (int kb = 0; kb < 4; kb++) {
                f16x8 af = *(const f16x8*)&laxh[(16 * m + (l & 15)) * LAXP + kb * 32 + (l >> 4) * 8];
                f16x8 bf = w1f[(nt * 4 + kb) * 64 + l];
                accv = __builtin_amdgcn_mfma_f32_16x16x32_f16(af, bf, accv, 0, 0, 0);
            }
            int n = nt * 16 + (l & 15);
            float bn = b1[n], vn = v[n];
            #pragma unroll
            for (int r = 0; r < 4; r++) {
                float p = fmaxf(accv[r] + bn, 0.f) * vn;
                p += __shfl_xor(p, 1, 64);
                p += __shfl_xor(p, 2, 64);
                p += __shfl_xor(p, 4, 64);
                p += __shfl_xor(p, 8, 64);
                rs[r] += p;
            }
        }
        if ((l & 15) == 0) {
            int q = l >> 4;
            #pragma unroll
            for (int r = 0; r < 4; r++)
                redm[(16 * m + q * 4 + r) * 2 + nh] = rs[r];
        }
    }
    __syncthreads();
    if (tid < 64) {
        int node = node0 + tid;
        if (node < N_NODES)
            z2[node] = rsqrtf((float)deg[node] + 1.f) * (redm[tid * 2] + redm[tid * 2 + 1]);
    }
}

// ---- aggregation: edge blocks -> LDS bins -> partials; graph blocks -> node term ----
__global__ void k_aggz(const float* __restrict__ z2, const int* __restrict__ deg,
                       const int* __restrict__ ei, const int* __restrict__ batch,
                       float* __restrict__ gpartE, float* __restrict__ gpartN,
                       int* __restrict__ gcnt) {
    int bid = blockIdx.x, t = threadIdx.x;
    if (bid < AGG_EB) {
        __shared__ float bs[4][NG];
        bs[t >> 6][t & 63] = 0.f;
        __syncthreads();
        int wg = t >> 6;
        for (int base = bid * 1024; base < N_EDGES; base += AGG_EB * 1024) {
            #pragma unroll
            for (int k = 0; k < 4; k++) {
                int e = base + k * 256 + t;
                if (e < N_EDGES) {
                    int s = ei[e];
                    int d = ei[N_EDGES + e];
                    float dv = rsqrtf((float)deg[d] + 1.f);
                    atomicAdd(&bs[wg][batch[d]], dv * z2[s]);
                }
            }
        }
        __syncthreads();
        if (t < NG) gpartE[bid * NG + t] = bs[0][t] + bs[1][t] + bs[2][t] + bs[3][t];
    } else {
        __shared__ int range[2];
        __shared__ float rs[4];
        int g = bid - AGG_EB;
        if (t < 2) {
            int key = g + t;
            int lo = 0, hi = N_NODES;
            while (lo < hi) { int m = (lo + hi) >> 1; if (batch[m] < key) lo = m + 1; else hi = m; }
            range[t] = lo;
        }
        __syncthreads();
        int lo = range[0], hi = range[1];
        float loc = 0.f;
        for (int i = lo + t; i < hi; i += 256)
            loc += rsqrtf((float)deg[i] + 1.f) * z2[i];
        #pragma unroll
        for (int off = 32; off > 0; off >>= 1) loc += __shfl_down(loc, off, 64);
        if ((t & 63) == 0) rs[t >> 6] = loc;
        __syncthreads();
        if (t == 0) {
            gpartN[g] = rs[0] + rs[1] + rs[2] + rs[3];
            gcnt[g] = hi - lo;
        }
    }
}

// ---- finalize ----
__global__ void k_final(const float* __restrict__ gpartE, const float* __restrict__ gpartN,
                        const int* __restrict__ gcnt, const float* __restrict__ beta2,
                        const float* __restrict__ bcin, float* __restrict__ out) {
    __shared__ float acc[4][NG];
    int t = threadIdx.x;
    int g = t & 63, c = t >> 6;
    float s = 0.f;
    for (int k = 0; k < AGG_EB / 4; k++)
        s += gpartE[(c * (AGG_EB / 4) + k) * NG + g];
    acc[c][g] = s;
    __syncthreads();
    if (t < NG) {
        float tot = acc[0][t] + acc[1][t] + acc[2][t] + acc[3][t] + gpartN[t];
        int cnt = gcnt[t];
        float val = tot / (float)(cnt > 0 ? cnt : 1) + beta2[0] + bcin[0];
        out[t] = 1.f / (1.f + expf(-val));
    }
}

extern "C" void kernel_launch(void* const* d_in, const int* in_sizes, int n_in,
                              void* d_out, int out_size, void* d_ws, size_t ws_size,
                              hipStream_t stream) {
    const float* x   = (const float*)d_in[0];
    const int*   ei  = (const int*)  d_in[1];
    const int*   bat = (const int*)  d_in[2];
    const float* W1  = (const float*)d_in[3];
    const float* b1  = (const float*)d_in[4];
    const float* W2  = (const float*)d_in[5];
    const float* b2  = (const float*)d_in[6];
    const float* Wc  = (const float*)d_in[7];
    const float* bc  = (const float*)d_in[8];
    float* out = (float*)d_out;

    char* w = (char*)d_ws;
    size_t off = 0;
    auto alloc = [&](size_t bytes) -> void* {
        void* p = w + off;
        off = (off + bytes + 255) & ~(size_t)255;
        return p;
    };
    int*   binCnt  = (int*)  alloc(NBIN * 4);                     // zeroed
    int*   binCur  = (int*)  alloc(NBIN * 4);                     // zeroed
    size_t zero_len = off;
    int*   binOff  = (int*)  alloc(NBIN * 4);
    int*   deg     = (int*)  alloc(N_NODES * 4);
    float* z2      = (float*)alloc(N_NODES * 4);
    float* v       = (float*)alloc(DIM * 4);
    float* beta2   = (float*)alloc(4);
    float* gpartE  = (float*)alloc((size_t)AGG_EB * NG * 4);
    float* gpartN  = (float*)alloc(NG * 4);
    int*   gcnt    = (int*)  alloc(NG * 4);
    f16x8* w1f     = (f16x8*)alloc(2048 * 16);                    // 32 KB
    unsigned int* xq     = (unsigned int*)alloc((size_t)N_NODES * DIM);     // 6.4 MB fp8
    unsigned int* sorted = (unsigned int*)alloc((size_t)N_EDGES * 4);       // 3.2 MB
    unsigned int* csr    = (unsigned int*)alloc((size_t)N_NODES * CAP * 4); // 9.6 MB
    (void)ws_size; (void)in_sizes; (void)n_in; (void)out_size;

    hipMemsetAsync(d_ws, 0, zero_len, stream);

    dim3 b256(256);
    k_prep<<<dim3(SORT_B + CAST_B + VB_B + WF_B), b256, 0, stream>>>(
        ei, binCnt, (const float4*)x, (uint4*)xq, W2, Wc, b2, v, beta2, W1, w1f);
    k_scatter<<<dim3(SORT_B), b256, 0, stream>>>(ei, binCnt, binCur, binOff, sorted);
    k_deg<<<dim3(NBIN), b256, 0, stream>>>(sorted, binOff, deg);
    k_build<<<dim3(NBIN), b256, 0, stream>>>(sorted, binOff, deg, csr);
    k_node<<<dim3(NODE_B), dim3(512), 0, stream>>>(
        (const uint4*)xq, csr, w1f, b1, v, deg, z2);
    k_aggz<<<dim3(AGG_EB + NG), b256, 0, stream>>>(z2, deg, ei, bat, gpartE, gpartN, gcnt);
    k_final<<<dim3(1), b256, 0, stream>>>(gpartE, gpartN, gcnt, beta2, bc, out);
}

// Round 16
// 172.501 us; speedup vs baseline: 1.0045x; 1.0045x over previous
//
#include <hip/hip_runtime.h>
#include <hip/hip_bf16.h>
#include <hip/hip_fp16.h>

#define N_NODES 50000
#define N_EDGES 800000
#define DIM     128
#define NG      64
#define GN      16     // nodes per k_node block (3125 blocks exact)
#define CAP     48     // CSR capacity/node (multiple of 8 and 4)
#define LAXP    136    // padded lax stride (f16 elems)

#define NBIN    196    // ceil(50000/256) bins of 256 nodes (dst>>8)
#define SORT_B  250    // S1/S3 blocks
#define EPB     3200   // edges per sort block (250*3200 = 800000 exact)

#define CAST_B  1563   // ceil(400000/256)
#define VB_B    129
#define WF_B    8

typedef float  f2_t  __attribute__((ext_vector_type(2)));
typedef float  f32x4 __attribute__((ext_vector_type(4)));
typedef _Float16 f16x8 __attribute__((ext_vector_type(8)));
typedef _Float16 f16x4 __attribute__((ext_vector_type(4)));

// ---- prep: S1 bin-count | cast x->fp8 | v=W2@Wc | W1->f16 B-fragments ----
__global__ void k_prep(const int* __restrict__ ei, int* __restrict__ binCnt,
                       const float4* __restrict__ x4, uint4* __restrict__ xq4,
                       const float* __restrict__ W2, const float* __restrict__ Wc,
                       const float* __restrict__ b2, float* __restrict__ v,
                       float* __restrict__ beta2,
                       const float* __restrict__ W1, f16x8* __restrict__ w1f) {
    __shared__ float red[4];
    __shared__ int hist[256];
    int bid = blockIdx.x, t = threadIdx.x;
    if (bid < SORT_B) {
        hist[t] = 0;
        __syncthreads();
        int base = bid * EPB;
        for (int r = 0; r < 13; r++) {
            int idx = r * 256 + t;
            if (idx < EPB) {
                int d = ei[N_EDGES + base + idx];
                atomicAdd(&hist[d >> 8], 1);
            }
        }
        __syncthreads();
        if (t < NBIN && hist[t] > 0) atomicAdd(&binCnt[t], hist[t]);
    } else if (bid < SORT_B + CAST_B) {
        int idx = (bid - SORT_B) * 256 + t;  // 16 dims/thread
        if (idx < N_NODES * DIM / 16) {
            uint4 o;
            unsigned* op = (unsigned*)&o;
            #pragma unroll
            for (int q = 0; q < 4; q++) {
                float4 f = x4[idx * 4 + q];
                int p = 0;
                p = __builtin_amdgcn_cvt_pk_fp8_f32(f.x, f.y, p, false);
                p = __builtin_amdgcn_cvt_pk_fp8_f32(f.z, f.w, p, true);
                op[q] = (unsigned)p;
            }
            xq4[idx] = o;
        }
    } else if (bid < SORT_B + CAST_B + VB_B) {
        int b = bid - (SORT_B + CAST_B);     // 0..128
        float p = 0.f;
        if (t < DIM) p = (b < DIM) ? W2[b * DIM + t] * Wc[t] : b2[t] * Wc[t];
        #pragma unroll
        for (int off = 32; off > 0; off >>= 1) p += __shfl_down(p, off, 64);
        if ((t & 63) == 0) red[t >> 6] = p;
        __syncthreads();
        if (t == 0) {
            float s = red[0] + red[1];
            if (b < DIM) v[b] = s; else beta2[0] = s;
        }
    } else {
        // W1 -> B-fragment layout for mfma_f32_16x16x32_f16
        int idx = (bid - (SORT_B + CAST_B + VB_B)) * 256 + t;   // 0..2047
        int ntile = idx >> 8, kb = (idx >> 6) & 3, l = idx & 63;
        int kbase = kb * 32 + (l >> 4) * 8;
        int n = ntile * 16 + (l & 15);
        f16x8 o;
        #pragma unroll
        for (int j = 0; j < 8; j++) o[j] = (_Float16)W1[(kbase + j) * DIM + n];
        w1f[idx] = o;
    }
}

// ---- S3 (scan fused in): per-block scan of binCnt, claim ranges, scatter ----
__global__ void k_scatter(const int* __restrict__ ei, const int* __restrict__ binCnt,
                          int* __restrict__ binCur, int* __restrict__ binOff,
                          unsigned int* __restrict__ sorted) {
    __shared__ int soff[256];
    __shared__ int hist[256];
    __shared__ int cur[256];
    int bid = blockIdx.x, t = threadIdx.x;
    int c = (t < NBIN) ? binCnt[t] : 0;
    soff[t] = c;
    #pragma unroll
    for (int o = 1; o < 256; o <<= 1) {
        __syncthreads();
        int v2 = (t >= o) ? soff[t - o] : 0;
        __syncthreads();
        soff[t] += v2;
    }
    __syncthreads();
    int excl = soff[t] - c;
    if (bid == 0 && t < NBIN) binOff[t] = excl;
    hist[t] = 0;
    __syncthreads();
    int base = bid * EPB;
    for (int r = 0; r < 13; r++) {
        int idx = r * 256 + t;
        if (idx < EPB) {
            int d = ei[N_EDGES + base + idx];
            atomicAdd(&hist[d >> 8], 1);
        }
    }
    __syncthreads();
    if (t < NBIN && hist[t] > 0) cur[t] = excl + atomicAdd(&binCur[t], hist[t]);
    __syncthreads();
    for (int r = 0; r < 13; r++) {
        int idx = r * 256 + t;
        if (idx < EPB) {
            int e = base + idx;
            int s = ei[e];
            int d = ei[N_EDGES + e];
            int pos = atomicAdd(&cur[d >> 8], 1);
            sorted[pos] = (unsigned)s | ((unsigned)(d & 255) << 16);
        }
    }
}

// ---- S4a: per-node degree from bin-sorted edges (LDS count) ----
__global__ void k_deg(const unsigned int* __restrict__ sorted,
                      const int* __restrict__ binOff, int* __restrict__ deg) {
    __shared__ int cnt[256];
    int b = blockIdx.x, t = threadIdx.x;
    cnt[t] = 0;
    __syncthreads();
    int lo = binOff[b];
    int hi = (b == NBIN - 1) ? N_EDGES : binOff[b + 1];
    for (int i = lo + t; i < hi; i += 256)
        atomicAdd(&cnt[sorted[i] >> 16], 1);
    __syncthreads();
    int node = b * 256 + t;
    if (node < N_NODES) deg[node] = cnt[t];
}

// ---- S4b: build stamped CSR (LDS cursors; deg[src] plain load) ----
__global__ void k_build(const unsigned int* __restrict__ sorted,
                        const int* __restrict__ binOff, const int* __restrict__ deg,
                        unsigned int* __restrict__ csr) {
    __shared__ int cur[256];
    int b = blockIdx.x, t = threadIdx.x;
    cur[t] = 0;
    __syncthreads();
    int lo = binOff[b];
    int hi = (b == NBIN - 1) ? N_EDGES : binOff[b + 1];
    for (int i = lo + t; i < hi; i += 256) {
        unsigned e = sorted[i];
        unsigned src = e & 0xFFFFu;
        unsigned dLow = e >> 16;
        int pos = atomicAdd(&cur[dLow], 1);
        if (pos < CAP) {
            float w = rsqrtf((float)deg[src] + 1.f);
            unsigned hw = (unsigned)__half_as_ushort(__float2half(w));
            csr[(b * 256 + dLow) * CAP + pos] = src | (hw << 16);
        }
    }
}

// ---- fused: gather(fp8 x) -> MFMA @W1 -> relu -> dot v -> z2 (R14 version) ----
__global__ __launch_bounds__(512) void k_node(
    const unsigned int* __restrict__ xq,    // fp8 x; row = 32 uints
    const unsigned int* __restrict__ csr,   // packed src|f16w
    const f16x8* __restrict__ w1f,          // W1 B-fragments
    const float* __restrict__ b1,
    const float* __restrict__ v, const int* __restrict__ deg,
    float* __restrict__ z2) {
    __shared__ _Float16 laxh[GN * LAXP];
    __shared__ float redm[GN * 8];
    int tid = threadIdx.x;
    int w = tid >> 6, l = tid & 63;
    int half = l >> 5, hl = l & 31;
    int node0 = blockIdx.x * GN;

    {
        int i = node0 + 2 * w + half;
        int len = min(deg[i], CAP);
        float di = rsqrtf((float)deg[i] + 1.f);

        unsigned su = xq[(size_t)i * 32 + hl];
        f2_t s01 = __builtin_amdgcn_cvt_pk_f32_fp8((int)su, false);
        f2_t s23 = __builtin_amdgcn_cvt_pk_f32_fp8((int)su, true);
        float ax[8], ay[8], az[8], aw[8];
        #pragma unroll
        for (int k = 0; k < 8; k++) { ax[k] = 0.f; ay[k] = 0.f; az[k] = 0.f; aw[k] = 0.f; }
        ax[0] = di * s01.x; ay[0] = di * s01.y;
        az[0] = di * s23.x; aw[0] = di * s23.y;

        int lenmax = max(len, __shfl_xor(len, 32, 64));   // wave-uniform
        int lmp = (lenmax + 7) & ~7;
        const uint4* csr4 = (const uint4*)csr;
        int base4 = i * (CAP / 4);
        for (int j = 0; j < lmp; j += 8) {
            uint4 ca = csr4[base4 + (j >> 2)];
            uint4 cb = csr4[base4 + (j >> 2) + 1];
            unsigned pe[8] = {ca.x, ca.y, ca.z, ca.w, cb.x, cb.y, cb.z, cb.w};
            unsigned q[8];
            #pragma unroll
            for (int k = 0; k < 8; k++)
                q[k] = xq[(size_t)(pe[k] & 0xFFFFu) * 32 + hl];
            float wgt[8];
            #pragma unroll
            for (int k = 0; k < 8; k++)
                wgt[k] = (j + k < len)
                    ? __half2float(__ushort_as_half((unsigned short)(pe[k] >> 16))) : 0.f;
            #pragma unroll
            for (int k = 0; k < 8; k++) {
                f2_t e01 = __builtin_amdgcn_cvt_pk_f32_fp8((int)q[k], false);
                f2_t e23 = __builtin_amdgcn_cvt_pk_f32_fp8((int)q[k], true);
                ax[k] = fmaf(wgt[k], e01.x, ax[k]);
                ay[k] = fmaf(wgt[k], e01.y, ay[k]);
                az[k] = fmaf(wgt[k], e23.x, az[k]);
                aw[k] = fmaf(wgt[k], e23.y, aw[k]);
            }
        }
        float a0 = 0.f, a1 = 0.f, a2 = 0.f, a3 = 0.f;
        #pragma unroll
        for (int k = 0; k < 8; k++) { a0 += ax[k]; a1 += ay[k]; a2 += az[k]; a3 += aw[k]; }
        f16x4 pk;
        pk[0] = (_Float16)(di * a0); pk[1] = (_Float16)(di * a1);
        pk[2] = (_Float16)(di * a2); pk[3] = (_Float16)(di * a3);
        *(f16x4*)&laxh[(2 * w + half) * LAXP + 4 * hl] = pk;
    }
    __syncthreads();

    f32x4 acc = {0.f, 0.f, 0.f, 0.f};
    #pragma unroll
    for (int kb = 0; kb < 4; kb++) {
        f16x8 af = *(const f16x8*)&laxh[(l & 15) * LAXP + kb * 32 + (l >> 4) * 8];
        f16x8 bf = w1f[(w * 4 + kb) * 64 + l];
        acc = __builtin_amdgcn_mfma_f32_16x16x32_f16(af, bf, acc, 0, 0, 0);
    }
    int n = w * 16 + (l & 15);
    float bn = b1[n], vn = v[n];
    #pragma unroll
    for (int r = 0; r < 4; r++) {
        float p = fmaxf(acc[r] + bn, 0.f) * vn;
        p += __shfl_xor(p, 1, 64);
        p += __shfl_xor(p, 2, 64);
        p += __shfl_xor(p, 4, 64);
        p += __shfl_xor(p, 8, 64);
        if ((l & 15) == 0) redm[((l >> 4) * 4 + r) * 8 + w] = p;
    }
    __syncthreads();
    if (tid < GN) {
        float s = 0.f;
        #pragma unroll
        for (int q = 0; q < 8; q++) s += redm[tid * 8 + q];
        z2[node0 + tid] = rsqrtf((float)deg[node0 + tid] + 1.f) * s;
    }
}

// ---- bin-centric aggregation + fused finalize (last-block-done) ----
__global__ void k_aggz(const float* __restrict__ z2, const int* __restrict__ deg,
                       const int* __restrict__ batch,
                       const unsigned int* __restrict__ sorted,
                       const int* __restrict__ binOff,
                       float* __restrict__ gpartE, float* __restrict__ gpartC,
                       int* __restrict__ done,
                       const float* __restrict__ beta2, const float* __restrict__ bcin,
                       float* __restrict__ out) {
    __shared__ float bs[NG];
    __shared__ float bc[NG];
    __shared__ int   batL[256];
    __shared__ float dvL[256];
    __shared__ int   lastFlag;
    int b = blockIdx.x, t = threadIdx.x;
    if (t < NG) { bs[t] = 0.f; bc[t] = 0.f; }
    int node = b * 256 + t;
    bool valid = (node < N_NODES);
    batL[t] = valid ? batch[node] : 0;
    dvL[t]  = valid ? rsqrtf((float)deg[node] + 1.f) : 0.f;
    __syncthreads();
    // node term + count
    if (valid) {
        atomicAdd(&bs[batL[t]], dvL[t] * z2[node]);
        atomicAdd(&bc[batL[t]], 1.f);
    }
    // edge term: stream this bin's sorted edges
    int lo = binOff[b];
    int hi = (b == NBIN - 1) ? N_EDGES : binOff[b + 1];
    for (int i = lo + t; i < hi; i += 256) {
        unsigned e = sorted[i];
        unsigned src = e & 0xFFFFu;
        unsigned dLow = e >> 16;
        atomicAdd(&bs[batL[dLow]], dvL[dLow] * z2[src]);
    }
    __syncthreads();
    if (t < NG) {
        gpartE[b * NG + t] = bs[t];
        gpartC[b * NG + t] = bc[t];
    }
    // last-block-done: final reduce + sigmoid
    if (t == 0) {
        __threadfence();
        lastFlag = (atomicAdd(done, 1) == NBIN - 1) ? 1 : 0;
    }
    __syncthreads();
    if (lastFlag) {
        __threadfence();     // acquire all partials
        if (t < NG) {
            float s = 0.f, c = 0.f;
            for (int k = 0; k < NBIN; k++) {
                s += gpartE[k * NG + t];
                c += gpartC[k * NG + t];
            }
            float val = (c > 0.5f) ? (s / c + beta2[0] + bcin[0]) : bcin[0];
            out[t] = 1.f / (1.f + expf(-val));
        }
    }
}

extern "C" void kernel_launch(void* const* d_in, const int* in_sizes, int n_in,
                              void* d_out, int out_size, void* d_ws, size_t ws_size,
                              hipStream_t stream) {
    const float* x   = (const float*)d_in[0];
    const int*   ei  = (const int*)  d_in[1];
    const int*   bat = (const int*)  d_in[2];
    const float* W1  = (const float*)d_in[3];
    const float* b1  = (const float*)d_in[4];
    const float* W2  = (const float*)d_in[5];
    const float* b2  = (const float*)d_in[6];
    const float* Wc  = (const float*)d_in[7];
    const float* bc  = (const float*)d_in[8];
    float* out = (float*)d_out;

    char* w = (char*)d_ws;
    size_t off = 0;
    auto alloc = [&](size_t bytes) -> void* {
        void* p = w + off;
        off = (off + bytes + 255) & ~(size_t)255;
        return p;
    };
    int*   binCnt  = (int*)  alloc(NBIN * 4);                     // zeroed
    int*   binCur  = (int*)  alloc(NBIN * 4);                     // zeroed
    int*   done    = (int*)  alloc(4);                            // zeroed
    size_t zero_len = off;
    int*   binOff  = (int*)  alloc(NBIN * 4);
    int*   deg     = (int*)  alloc(N_NODES * 4);
    float* z2      = (float*)alloc(N_NODES * 4);
    float* v       = (float*)alloc(DIM * 4);
    float* beta2   = (float*)alloc(4);
    float* gpartE  = (float*)alloc((size_t)NBIN * NG * 4);
    float* gpartC  = (float*)alloc((size_t)NBIN * NG * 4);
    f16x8* w1f     = (f16x8*)alloc(2048 * 16);                    // 32 KB
    unsigned int* xq     = (unsigned int*)alloc((size_t)N_NODES * DIM);     // 6.4 MB fp8
    unsigned int* sorted = (unsigned int*)alloc((size_t)N_EDGES * 4);       // 3.2 MB
    unsigned int* csr    = (unsigned int*)alloc((size_t)N_NODES * CAP * 4); // 9.6 MB
    (void)ws_size; (void)in_sizes; (void)n_in; (void)out_size;

    hipMemsetAsync(d_ws, 0, zero_len, stream);

    dim3 b256(256);
    k_prep<<<dim3(SORT_B + CAST_B + VB_B + WF_B), b256, 0, stream>>>(
        ei, binCnt, (const float4*)x, (uint4*)xq, W2, Wc, b2, v, beta2, W1, w1f);
    k_scatter<<<dim3(SORT_B), b256, 0, stream>>>(ei, binCnt, binCur, binOff, sorted);
    k_deg<<<dim3(NBIN), b256, 0, stream>>>(sorted, binOff, deg);
    k_build<<<dim3(NBIN), b256, 0, stream>>>(sorted, binOff, deg, csr);
    k_node<<<dim3(N_NODES / GN), dim3(512), 0, stream>>>(
        xq, csr, w1f, b1, v, deg, z2);
    k_aggz<<<dim3(NBIN), b256, 0, stream>>>(
        z2, deg, bat, sorted, binOff, gpartE, gpartC, done, beta2, bc, out);
}